// Round 14
// baseline (815.710 us; speedup 1.0000x reference)
//
#include <hip/hip_runtime.h>

// FSMN depthwise strided FIR — R14: persistent 16-tile blocks, pow2 x-ring,
// compile-time slot math everywhere. B=32, T=2000, D=512, L=R=20, stride 2.
//
// R13 post-mortem: cap-128 spilled 3rd time -> body needs ~200 VGPR; only
// clean regime = 256thr + lb(256,1) -> 1 block/CU. So: cut per-block work.
// R7's 19k cy/16-m includes ~8k exposed prologue DMA (89KB/block, cold).
// R14 amortizes it: 256 blocks (1/CU) x 16 tiles. Per tile: 32 new x rows
// + 34 filt rows (L2-hot) staged, vs R7's 112+41 cold.
//
// x ring XR=128 (slot = (32k + rel)&127). In the 4-tile unrolled group
// (k = 4g+j), tbm = (32k)&127 = 32j — COMPILE-TIME, independent of g
// (R12's runtime-tbm spill trigger eliminated; &127 add+and per read is
// R7/R9's proven-clean pattern).
//
// Tile-k frame: rel r = abs x row - (R00 + 32k), window span rel 0..110.
// Wave mg: base wb = 32j + 8mg; init reads rel 8mg..8mg+7; E push
// rel 8mg+2t+8; O push +-1; O holds t=20 (refcheck'd R4..R13).
//
// x staging liveness (verified):
//  - rel 112..127 -> slots (tbm-16..-1)&127, last read tile k-1 t<=11
//    (as its rel 16..31) => stage at TILE START (4+ barriers margin).
//    First read: tile k+1 (rel' 80..95) t>=24 => drained long before.
//  - rel 128..143 -> slots (tbm..+15)&127 = this tile's rel 0..15: last
//    read t<=3 (init + early pushes) => stage at PHASE-1 start (t=8).
//    First read tile k+1 (rel' 96..111) t>=32.
// Filt ring FRG=24 (slot = row%24; rows 17..23 map uniquely -> staged once
// in prologue, never again). Slots 0..16 carry row r then r+24 per tile:
//  - row 24+s stage after row s dead (t=s): rows 24..31 @phase1 (t>=8),
//    32..39 @phase2 (t>=16), 40 @phase3 (t>=24).
//  - row s restore after row 24+s dead (t=24+s): rows 0..7 @phase4
//    (t>=32), 8..15 @tail (t>=40), row 16 @next tile start (row 40's
//    last read t=40; slot 16 read next tile at t=14, 1 barrier after).
// Phases: 5 x 8 steps (t=0..39) + tail t=40 + stores; 6 barriers/tile.
// Every stage: >=1 barrier after target's last read, >=1 before first read.
//
// Spill ledger: clean = 256thr+lb(256,1) natural 256 (R7/R9); spill =
// cap128 x3, 512thr x2, runtime-ring (R12). R14: lb(256,1), compile-time
// slots, running ptrs advanced by consts. Tell: FETCH >= 400MB.

#define B_ 32
#define T_ 2000
#define D_ 512
#define S_ 1000   // T/2
#define M_ 4      // m per thread
#define TM 16     // m per tile
#define TILES 16  // tiles per block
#define SEG 256   // m per block (segment)
#define FRG 24    // filt ring rows
#define FOFF 0
#define XOFF (FRG * 256)
#define XR 128
#define LDS_FLOATS (XOFF + XR * 256)   // 152 KB

__device__ __forceinline__ float4 zf4() {
    float4 z; z.x = 0.f; z.y = 0.f; z.z = 0.f; z.w = 0.f; return z;
}

__device__ __forceinline__ void fma4(float4& a, const float4 f, const float4 w) {
    a.x = fmaf(f.x, w.x, a.x);
    a.y = fmaf(f.y, w.y, a.y);
    a.z = fmaf(f.z, w.z, a.z);
    a.w = fmaf(f.w, w.w, a.w);
}

// Async global->LDS DMA: 16B/lane x 64 lanes = one 1KB row per call.
__device__ __forceinline__ void gload_lds16(const float* g, float* l) {
    __builtin_amdgcn_global_load_lds(
        (const __attribute__((address_space(1))) void*)g,
        (__attribute__((address_space(3))) void*)l,
        16, 0, 0);
}

__global__ __launch_bounds__(256, 1) void fsmn_kernel(
    const float* __restrict__ x, const float* __restrict__ filt,
    float* __restrict__ out)
{
    __shared__ float lds[LDS_FLOATS];      // 152 KB: filt ring 24 + x ring 128

    const int lane = threadIdx.x;          // 0..63
    const int mg   = threadIdx.y;          // 0..3 : wave id

    // 256 blocks = 8 XCDs x 32 CUs.
    const int bid = blockIdx.x;
    const int n   = (bid & 7) * 32 + (bid >> 3);   // 0..255
    const int seg = n & 3;                 // 256-m segment
    const int dh  = (n >> 2) & 1;          // d-half
    const int b   = n >> 3;                // batch

    const int m0seg = seg * SEG;
    const int d  = (dh * 64 + lane) * 4;
    const float* xb = x + (size_t)b * T_ * D_ + d;
    const float* fb = filt + d;
    float*       ob = out + (size_t)b * T_ * D_ + d;
    const int R00 = 2 * m0seg - 40;        // abs x row of tile-0 rel 0

    // ---- helpers (slot always in [0,128) / [0,24), wave-uniform rows) ----
    auto stgX = [&](const float* g, int slot, int row) {
        float* l = lds + XOFF + (slot << 8);
        if ((unsigned)row < (unsigned)T_) gload_lds16(g, l);
        else *(float4*)(l + lane * 4) = zf4();
    };
    auto stgF = [&](int row, int slot) {   // filt rows always in-bounds if <=40
        if (row <= 40)
            gload_lds16(fb + (size_t)row * D_, lds + FOFF + (slot << 8));
    };
    auto ldrow = [&](int slot) -> float4 { // caller applies &127
        return *(const float4*)(lds + XOFF + (slot << 8) + lane * 4);
    };
    auto ldF = [&](int t) -> float4 {      // t compile-time -> slot const
        return *(const float4*)(lds + FOFF + ((t % FRG) << 8) + lane * 4);
    };

    // ---- Prologue (once): filt rows 0..23 (slot=row) + x rel 0..111 ----
#pragma unroll
    for (int i = 0; i < 6; ++i) {
        const int fr = 6 * mg + i;         // 0..23
        gload_lds16(fb + (size_t)fr * D_, lds + FOFF + (fr << 8));
    }
#pragma unroll
    for (int i = 0; i < 28; ++i) {
        const int r = 4 * i + mg;          // 0..111, slot == r (tbm=0)
        stgX(xb + (size_t)(R00 + r) * D_, r, R00 + r);
    }
    __syncthreads();

    // ---- Running state (advanced by constants only) ----
    const float* pxs = xb + (size_t)(R00 + 112 + 4 * mg) * D_;  // x stage base
    int   xrow = R00 + 112 + 4 * mg;       // staging guard row
    float* po  = ob + (size_t)(2 * (m0seg + 4 * mg)) * D_;      // store base
    int   m0w  = m0seg + 4 * mg;           // wave's first m this tile

#pragma unroll 1
    for (int g = 0; g < TILES / 4; ++g) {
#pragma unroll
        for (int j = 0; j < 4; ++j) {      // tbm = 32*j (compile-time)
            const int wb = 32 * j + 8 * mg;

            // -- tile start: x rel 112..127 (4/wave) + filt row-16 restore --
#pragma unroll
            for (int i = 0; i < 4; ++i)
                stgX(pxs + (size_t)i * D_, (32 * j + 112 + 4 * mg + i) & 127,
                     xrow + i);
            if (mg == 0) stgF(16, 16);

            // -- init windows + filter queue --
            float4 wE[M_], wO[M_], ae[M_], ao[M_];
#pragma unroll
            for (int m = 0; m < M_; ++m) {
                wE[m] = ldrow((wb + 2 * m) & 127);
                wO[m] = ldrow((wb + 2 * m + 1) & 127);
                ae[m] = zf4(); ao[m] = zf4();
            }
            float4 qF0 = ldF(0), qF1 = ldF(1);

            auto dostep = [&](int t) {     // t compile-time under unroll
                const float4 fv = qF0;
                qF0 = qF1;
                qF1 = (t + 2 <= 40) ? ldF(t + 2) : zf4();
                if (t <= 20) {
#pragma unroll
                    for (int m = 0; m < M_; ++m) { fma4(ae[m], fv, wE[m]); fma4(ao[m], fv, wO[m]); }
                } else {
#pragma unroll
                    for (int m = 0; m < M_; ++m) { fma4(ao[m], fv, wE[m]); fma4(ae[m], fv, wO[m]); }
                }
                if (t < 40) {
#pragma unroll
                    for (int m = 0; m < M_ - 1; ++m) wE[m] = wE[m + 1];
                    wE[M_ - 1] = ldrow((wb + 2 * t + 8) & 127);
                    if (t != 20) {
#pragma unroll
                        for (int m = 0; m < M_ - 1; ++m) wO[m] = wO[m + 1];
                        wO[M_ - 1] = ldrow((wb + 2 * t + 8 + ((t < 20) ? 1 : -1)) & 127);
                    }
                }
            };

            // -- phase 0: t=0..7 --
#pragma unroll
            for (int t = 0; t < 8; ++t) dostep(t);
            __syncthreads();
            // -- phase 1: x rel 128..143 + filt rows 24..31 --
#pragma unroll
            for (int i = 0; i < 4; ++i)
                stgX(pxs + (size_t)(16 + i) * D_, (32 * j + 4 * mg + i) & 127,
                     xrow + 16 + i);
            stgF(24 + 2 * mg, 2 * mg);
            stgF(25 + 2 * mg, 2 * mg + 1);
#pragma unroll
            for (int t = 8; t < 16; ++t) dostep(t);
            __syncthreads();
            // -- phase 2: filt rows 32..39 --
            stgF(32 + 2 * mg, 8 + 2 * mg);
            stgF(33 + 2 * mg, 9 + 2 * mg);
#pragma unroll
            for (int t = 16; t < 24; ++t) dostep(t);
            __syncthreads();
            // -- phase 3: filt row 40 (mg0 only via guard) --
            stgF(40 + 2 * mg, 16 + 2 * mg);
#pragma unroll
            for (int t = 24; t < 32; ++t) dostep(t);
            __syncthreads();
            // -- phase 4: filt rows 0..7 restore --
            stgF(2 * mg, 2 * mg);
            stgF(2 * mg + 1, 2 * mg + 1);
#pragma unroll
            for (int t = 32; t < 40; ++t) dostep(t);
            __syncthreads();
            // -- tail: filt rows 8..15 restore + t=40 + stores --
            stgF(8 + 2 * mg, 8 + 2 * mg);
            stgF(9 + 2 * mg, 9 + 2 * mg);
            dostep(40);
#pragma unroll
            for (int m = 0; m < M_; ++m) {
                if (m0w + m < S_) {
                    *(float4*)(po + (size_t)(2 * m)     * D_) = ae[m];
                    *(float4*)(po + (size_t)(2 * m + 1) * D_) = ao[m];
                }
            }
            __syncthreads();               // tile end: drain DMA, fence ring

            pxs += (size_t)32 * D_;  xrow += 32;
            po  += (size_t)32 * D_;  m0w  += TM;
        }
    }
}

extern "C" void kernel_launch(void* const* d_in, const int* in_sizes, int n_in,
                              void* d_out, int out_size, void* d_ws, size_t ws_size,
                              hipStream_t stream) {
    const float* x    = (const float*)d_in[0];
    const float* filt = (const float*)d_in[1];
    float*       out  = (float*)d_out;

    dim3 block(64, 4, 1);
    // 32 batches x 2 d-halves x 4 segments = 256 persistent blocks (1/CU).
    dim3 grid(256, 1, 1);
    hipLaunchKernelGGL(fsmn_kernel, grid, block, 0, stream, x, filt, out);
}

// Round 15
// 287.241 us; speedup vs baseline: 2.8398x; 2.8398x over previous
//
#include <hip/hip_runtime.h>

// FSMN depthwise strided FIR — R15: R7's clean shape scaled to M_=6.
// B=32, T=2000, D=512, L=R=20, stride 2.
//
// R14 post-mortem: multi-tile unrolled bodies spill (164-step region,
// live ranges leak across tiles), on top of runtime-ring spill (R12) and
// cap-128 spill (R8/R13) and 512-thr pin (R10/R11). Persistence is
// unreachable. Clean regime = single-tile unrolled body, 256 thr,
// lb(256,1) — R7 (125us). R15 scales THAT: 24 m per block (M_=6).
//
// Why it should win: staged rows per output row 4.78 -> 3.52 (-26% DMA);
// blocks/CU 15.75 -> 10.5 (-52% exposed prologue rows per CU); per-step
// LDS reads unchanged (2 x-push + 1 filt per wave-step); FMA x1.5.
// No new spill trigger: x buffer is CONTIGUOUS 128 rows (slot = rel row,
// no ring, no AND, no runtime base); filt ring = R10's verified 24-row
// 3-chunk scheme with compile-time slots.
//
// Geometry: wave mg covers m = m0b + 6mg .. +5. rel = abs x row - R0,
// R0 = 2*m0b - 40. E window at step t: rel = 12mg + 2t + 2m (m=0..5);
// O: +1 (t<=20) / -1 (t>=21, holds at t=20). E push rel = 12mg+2t+12;
// O push +-1. Max rel read = 126 (mg=3,t=39); init max 47; all in 0..127.
//
// Staging plan (5 phases x 8 steps, t=0..39, tail t=40):
//   prologue: x rel 0..63 (16/wave) + filt chunks 0,1 (rows 0..15); sync.
//   phase p (p=0..3) start: x chunk p+4 (rows 16(p+4)..+15, 4/wave) and
//     filt chunk p+2 (rows 8(p+2)+2mg,+1, guard <=40 -> row 40 only mg0).
//   x liveness: chunk c first read (E/O push) needs 12mg+2t+12 >= 16c
//     -> earliest t = 8(c-4)+8 = phase c-3 start; staged phase c-4,
//     drained by that phase's END barrier => >=1 barrier margin. Init
//     reads (rel<=47) covered by prologue's 0..63.
//   filt liveness (R10 scheme): phase p reads rows 8p+2..8p+9 = chunks
//     p,p+1 (groups p%3,(p+1)%3); stage chunk p+2 -> group (p+2)%3
//     disjoint; overwrites chunk p-1, last read phase p-1 (1 barrier).
// Barriers: 5 per block (prologue + ends of phases 0..3). Stores at end.
//
// Spill ledger: clean = {R4 simple@128, R7/R9 single-tile@256}; spill =
// {cap128 x3, 512thr x2, runtime-ring, multi-tile}. R15: single-tile,
// lb(256,1), compile-time slots. Tell: FETCH >= 400MB -> revert R7.

#define B_ 32
#define T_ 2000
#define D_ 512
#define S_ 1000   // T/2
#define M_ 6      // m per thread (=> 12 output rows)
#define TM 24     // m per block
#define FRG 24    // filt ring rows
#define FOFF 0
#define XOFF (FRG * 256)
#define LDS_FLOATS (XOFF + 128 * 256)   // 152 KB

__device__ __forceinline__ float4 zf4() {
    float4 z; z.x = 0.f; z.y = 0.f; z.z = 0.f; z.w = 0.f; return z;
}

__device__ __forceinline__ void fma4(float4& a, const float4 f, const float4 w) {
    a.x = fmaf(f.x, w.x, a.x);
    a.y = fmaf(f.y, w.y, a.y);
    a.z = fmaf(f.z, w.z, a.z);
    a.w = fmaf(f.w, w.w, a.w);
}

// Async global->LDS DMA: 16B/lane x 64 lanes = one 1KB row per call.
__device__ __forceinline__ void gload_lds16(const float* g, float* l) {
    __builtin_amdgcn_global_load_lds(
        (const __attribute__((address_space(1))) void*)g,
        (__attribute__((address_space(3))) void*)l,
        16, 0, 0);
}

template<bool CHK>
__device__ __forceinline__ void fsmn_body(float* __restrict__ lds,
                                          const float* __restrict__ xb,
                                          const float* __restrict__ fb,
                                          float* __restrict__ ob,
                                          int m0w, int R0, int lane, int mg)
{
    // ---- staging helpers (row = compile-time const + mg terms; R7 pattern) ----
    auto stgX = [&](int rel) {             // slot == rel (contiguous, no ring)
        float* l = lds + XOFF + (rel << 8);
        const int row = R0 + rel;
        if (!CHK || (unsigned)row < (unsigned)T_)
            gload_lds16(xb + (size_t)row * D_, l);
        else
            *(float4*)(l + lane * 4) = zf4();
    };
    auto stgF = [&](int fr) {              // slot = fr % FRG (compile-time)
        if (fr <= 40)
            gload_lds16(fb + (size_t)fr * D_, lds + FOFF + ((fr % FRG) << 8));
    };
    auto ldrow = [&](int rel) -> float4 {
        return *(const float4*)(lds + XOFF + (rel << 8) + lane * 4);
    };
    auto ldF = [&](int t) -> float4 {      // t compile-time -> slot const
        return *(const float4*)(lds + FOFF + ((t % FRG) << 8) + lane * 4);
    };

    // ---- Prologue: x rel 0..63 (16/wave) + filt chunks 0,1 (rows 0..15) ----
#pragma unroll
    for (int i = 0; i < 16; ++i) stgX(4 * i + mg);
#pragma unroll
    for (int i = 0; i < 4; ++i) stgF(4 * mg + i);
    __syncthreads();                       // all prologue DMA done

    // ---- Init windows (rel <= 47) + filter queue ----
    float4 wE[M_], wO[M_], ae[M_], ao[M_];
#pragma unroll
    for (int m = 0; m < M_; ++m) {
        wE[m] = ldrow(12 * mg + 2 * m);
        wO[m] = ldrow(12 * mg + 2 * m + 1);
        ae[m] = zf4(); ao[m] = zf4();
    }
    float4 qF0 = ldF(0), qF1 = ldF(1);     // dist-2 LDS queue

    // ---- One step (tap filt[t]); t compile-time under unroll ----
    auto dostep = [&](int t) {
        const float4 fv = qF0;
        qF0 = qF1;
        qF1 = (t + 2 <= 40) ? ldF(t + 2) : zf4();
        if (t <= 20) {
#pragma unroll
            for (int m = 0; m < M_; ++m) { fma4(ae[m], fv, wE[m]); fma4(ao[m], fv, wO[m]); }
        } else {
#pragma unroll
            for (int m = 0; m < M_; ++m) { fma4(ao[m], fv, wE[m]); fma4(ae[m], fv, wO[m]); }
        }
        if (t < 40) {
#pragma unroll
            for (int m = 0; m < M_ - 1; ++m) wE[m] = wE[m + 1];
            wE[M_ - 1] = ldrow(12 * mg + 2 * t + 12);
            if (t != 20) {                 // O holds at junction
#pragma unroll
                for (int m = 0; m < M_ - 1; ++m) wO[m] = wO[m + 1];
                wO[M_ - 1] = ldrow(12 * mg + 2 * t + 12 + ((t < 20) ? 1 : -1));
            }
        }
    };

    // ---- Phases p=0..4 (8 steps each; phase 4 ends with tail t=40) ----
#pragma unroll
    for (int p = 0; p < 5; ++p) {
        if (p <= 3) {                      // stage one phase ahead
#pragma unroll
            for (int i = 0; i < 4; ++i)    // x chunk p+4 (4 rows/wave)
                stgX(16 * (p + 4) + 4 * mg + i);
            stgF(8 * (p + 2) + 2 * mg);    // filt chunk p+2 (2 rows/wave)
            stgF(8 * (p + 2) + 2 * mg + 1);
        }
#pragma unroll
        for (int t = 8 * p; t < ((p == 4) ? 41 : 8 * p + 8); ++t) dostep(t);
        if (p < 4) __syncthreads();        // drain DMA + fence ring reuse
    }

    // ---- Store 2*M_ output rows (coalesced float4 across 64 lanes) ----
#pragma unroll
    for (int m = 0; m < M_; ++m) {
        if (!CHK || (m0w + m) < S_) {
            *(float4*)(ob + (size_t)(2 * (m0w + m))     * D_) = ae[m];
            *(float4*)(ob + (size_t)(2 * (m0w + m) + 1) * D_) = ao[m];
        }
    }
}

__global__ __launch_bounds__(256, 1) void fsmn_kernel(
    const float* __restrict__ x, const float* __restrict__ filt,
    float* __restrict__ out)
{
    __shared__ float lds[LDS_FLOATS];      // 152 KB: filt ring 24 + x 128 rows

    const int lane = threadIdx.x;          // 0..63
    const int mg   = threadIdx.y;          // 0..3 : m-group (one wave each)

    // XCD-chunked swizzle: 2688 blocks = 8 XCDs x 336 (bijective).
    const int bid  = blockIdx.x;
    const int xcd  = bid & 7;
    const int slot = bid >> 3;
    const int n    = xcd * 336 + slot;
    const int mb   = n % 42;               // 0..41 : m-block (24 m each)
    const int rest = n / 42;
    const int dh   = rest & 1;             // d-half
    const int b    = rest >> 1;            // batch

    const int m0b = mb * TM;
    const int m0w = m0b + mg * M_;
    const int d   = (dh * 64 + lane) * 4;
    const float* xb = x + (size_t)b * T_ * D_ + d;
    const float* fb = filt + d;
    float*       ob = out + (size_t)b * T_ * D_ + d;
    const int R0  = 2 * m0b - 40;          // abs x row of rel 0

    // Interior iff staged rows rel 0..127 valid (R0>=0 -> mb>=1;
    // R0+127<=1999 -> mb<=39) and all stores valid (m0b+23 < 1000 ✓ mb<=39).
    // No early-return — all 256 threads reach every barrier.
    if (mb >= 1 && mb <= 39) fsmn_body<false>(lds, xb, fb, ob, m0w, R0, lane, mg);
    else                     fsmn_body<true >(lds, xb, fb, ob, m0w, R0, lane, mg);
}

extern "C" void kernel_launch(void* const* d_in, const int* in_sizes, int n_in,
                              void* d_out, int out_size, void* d_ws, size_t ws_size,
                              hipStream_t stream) {
    const float* x    = (const float*)d_in[0];
    const float* filt = (const float*)d_in[1];
    float*       out  = (float*)d_out;

    dim3 block(64, 4, 1);
    // 42 m-blocks (24 m each) x 2 d-halves x 32 batches = 2688 blocks.
    dim3 grid(2688, 1, 1);
    hipLaunchKernelGGL(fsmn_kernel, grid, block, 0, stream, x, filt, out);
}